// Round 6
// baseline (5972.535 us; speedup 1.0000x reference)
//
#include <hip/hip_runtime.h>
#include <stdint.h>

// Spiking neural network:
//   B=32 batches, S=1024 steps, I=256 inputs, H=512 hidden, O=256 outputs.
// Phase 0: pad wlat (f32) with a 513th all-zero row.
// Phase 1: ic[B*S, H] (f64) = x[B*S, I] @ Win[I, H]   (feeds spike decisions)
// Phase 2: 4-way column-split scan: 4 blocks per batch, each owns 128
//          columns/neurons; per-step spike-mask exchange via device-scope
//          release/acquire flags in workspace (write-once per (b,t,word),
//          poison 0xAA != 1 so no reset needed). All 128 blocks co-resident.
// Phase 3: out[B*S, O] (f32) = spikes @ Wout via bitmask-driven row sums.
//
// All decision-feeding arithmetic is f64 so spikes match an f64 numpy
// reference exactly; split/order nondeterminism only perturbs sums ~1e-15.

#define BB 32
#define SS 1024
#define II 256
#define HH 512
#define OO 256
#define ZEB (HH * HH * 4)   // byte offset of the all-zero row in wpad
#define NSPL 4
#define COLS 128            // columns per split block
#define NCH 32              // gather chunks (32 threads each: 32 quads x 4 cols)
#define ACTPAD 608          // active list capacity incl. rotation over-read

// ---------------- Phase 0: wlat -> padded f32 table with zero row ----------------
__global__ __launch_bounds__(256) void wlat_pad(const float* __restrict__ wlat,
                                                float* __restrict__ wpad) {
    const int i = blockIdx.x * 256 + threadIdx.x;
    const int total = (HH + 1) * HH;
    if (i < HH * HH) wpad[i] = wlat[i];
    else if (i < total) wpad[i] = 0.0f;
}

// ---------------- Phase 1: f64-accumulate tiled GEMM ----------------
#define TM 64
#define TN 64
#define TK 16

__global__ __launch_bounds__(256) void ic_gemm_f64(const float* __restrict__ x,
                                                   const float* __restrict__ win,
                                                   double* __restrict__ ic) {
    __shared__ float As[TK][TM + 4];
    __shared__ float Bs[TK][TN];
    const int tid = threadIdx.x;
    const int m0 = blockIdx.x * TM;
    const int n0 = blockIdx.y * TN;
    const int tx = tid & 15;
    const int ty = tid >> 4;

    double acc[4][4];
#pragma unroll
    for (int i = 0; i < 4; ++i)
#pragma unroll
        for (int j = 0; j < 4; ++j) acc[i][j] = 0.0;

    const int lr = tid >> 2;
    const int lq = tid & 3;
    const int br = tid >> 4;
    const int bq = tid & 15;

    for (int k0 = 0; k0 < II; k0 += TK) {
        float4 av = *(const float4*)(x + (size_t)(m0 + lr) * II + k0 + lq * 4);
        float4 bv = *(const float4*)(win + (size_t)(k0 + br) * HH + n0 + bq * 4);
        As[lq * 4 + 0][lr] = av.x;
        As[lq * 4 + 1][lr] = av.y;
        As[lq * 4 + 2][lr] = av.z;
        As[lq * 4 + 3][lr] = av.w;
        *(float4*)(&Bs[br][bq * 4]) = bv;
        __syncthreads();
#pragma unroll
        for (int kk = 0; kk < TK; ++kk) {
            float4 a = *(const float4*)(&As[kk][ty * 4]);
            float4 b = *(const float4*)(&Bs[kk][tx * 4]);
            const double a0 = (double)a.x, a1 = (double)a.y, a2 = (double)a.z, a3 = (double)a.w;
            const double b0 = (double)b.x, b1 = (double)b.y, b2 = (double)b.z, b3 = (double)b.w;
            acc[0][0] += a0 * b0; acc[0][1] += a0 * b1; acc[0][2] += a0 * b2; acc[0][3] += a0 * b3;
            acc[1][0] += a1 * b0; acc[1][1] += a1 * b1; acc[1][2] += a1 * b2; acc[1][3] += a1 * b3;
            acc[2][0] += a2 * b0; acc[2][1] += a2 * b1; acc[2][2] += a2 * b2; acc[2][3] += a2 * b3;
            acc[3][0] += a3 * b0; acc[3][1] += a3 * b1; acc[3][2] += a3 * b2; acc[3][3] += a3 * b3;
        }
        __syncthreads();
    }

#pragma unroll
    for (int i = 0; i < 4; ++i) {
        double* row = ic + (size_t)(m0 + ty * 4 + i) * HH + n0 + tx * 4;
#pragma unroll
        for (int j = 0; j < 4; ++j) row[j] = acc[i][j];
    }
}

// ---------------- Phase 2: 4-way split sequential scan ----------------
// Grid: 128 blocks x 1024 threads. bid = j*32 + b (j = column split 0..3).
// Gather: thread = (chunk ch = tid>>5, quad qd = tid&31); chunk ch processes
// active rows ch, ch+32, ... ; each thread reads 4 adjacent columns
// (16B dwordx4) of its block's 128-column slice. Zero-row padding makes the
// loop maskless; over-reads hit the L1-hot zero row.
// Masks: 8 u64 words per (b,t); block j produces words 2j, 2j+1; exchange
// via xm (data) + xf (flags, release/acquire, write-once, poll ==1).
__global__ __launch_bounds__(1024) void snn_scan4(const double* __restrict__ ic,
                                                  const float* __restrict__ wpad,
                                                  const float* __restrict__ thr,
                                                  uint64_t* __restrict__ xm,
                                                  uint32_t* __restrict__ xf) {
    __shared__ int s_act[2][ACTPAD];
    __shared__ int s_nact[2];
    __shared__ double s_part[NCH][COLS + 4];
    __shared__ uint64_t s_m8[8];

    const int tid = threadIdx.x;
    const int bid = blockIdx.x;
    const int b = bid & 31;
    const int j = bid >> 5;            // column split index 0..3
    const int qd = tid & 31;
    const int ch = tid >> 5;
    const int sw = (qd >> 2) & 3;      // LDS slot swizzle (kills 32B-stride conflicts)
    const int colb = (j << 9) + (qd << 4);  // byte offset within a 2048B row

    const double* icb = ic + (size_t)b * SS * HH + j * COLS;
    uint64_t* xmb = xm + (size_t)b * SS * 8;
    uint32_t* xfb = xf + (size_t)b * SS * 8;

    const bool owner = (tid < COLS);   // waves 0,1 own the 128 neurons
    double mp = 0.0;
    int refrac = 0;
    double th = 0.0;
    if (owner) th = (double)thr[j * COLS + tid];
    const int rsw = owner ? (tid ^ ((tid >> 4) & 3)) : 0;

    if (tid == 0) { s_nact[0] = 0; s_nact[1] = 0; }
    if (tid < ACTPAD) { s_act[0][tid] = ZEB; s_act[1][tid] = ZEB; }
    __syncthreads();

    int cur = 0;
    for (int t = 0; t < SS; ++t) {
        const int nxt = cur ^ 1;

        // ---- G phase: ic prefetch, re-pad next list, chunked gather ----
        double icv = 0.0;
        if (owner) icv = icb[(size_t)t * HH + tid];
        if (tid < ACTPAD) s_act[nxt][tid] = ZEB;  // last read 2+ barriers ago

        const int n = s_nact[cur];
        const int NB = (n + 31) >> 5;
        const int* act = s_act[cur];

        double ac0 = 0.0, ac1 = 0.0, ac2 = 0.0, ac3 = 0.0;
        {
            int idx = ch;
            float4 f0 = *(const float4*)((const char*)wpad + (unsigned)(act[idx] + colb));
            float4 f1 = *(const float4*)((const char*)wpad + (unsigned)(act[idx + 32] + colb));
            for (int k = 0; k < NB; ++k) {
                float4 f2 = *(const float4*)((const char*)wpad + (unsigned)(act[idx + 64] + colb));
                ac0 += (double)f0.x;
                ac1 += (double)f0.y;
                ac2 += (double)f0.z;
                ac3 += (double)f0.w;
                f0 = f1; f1 = f2; idx += 32;
            }
        }
        {
            const int base = qd << 2;
            s_part[ch][(base + 0) ^ sw] = ac0;
            s_part[ch][(base + 1) ^ sw] = ac1;
            s_part[ch][(base + 2) ^ sw] = ac2;
            s_part[ch][(base + 3) ^ sw] = ac3;
        }
        __syncthreads();  // B1: partials ready

        // ---- owners: reduce 32 partials, update, ballot, publish ----
        if (owner) {
            double l0 = 0.0, l1 = 0.0, l2 = 0.0, l3 = 0.0;
#pragma unroll
            for (int c = 0; c < NCH; c += 4) {
                l0 += s_part[c + 0][rsw];
                l1 += s_part[c + 1][rsw];
                l2 += s_part[c + 2][rsw];
                l3 += s_part[c + 3][rsw];
            }
            const double lat = (l0 + l1) + (l2 + l3);
            mp = 0.95 * mp + icv - lat;
            if (refrac > 0) mp = 0.0;
            refrac = (refrac > 0) ? (refrac - 1) : 0;
            const bool spike = (mp >= th);
            if (spike) { mp = 0.0; refrac = 2; }

            const uint64_t bm = __ballot(spike);
            if ((tid & 63) == 0) {
                const int word = 2 * j + (tid >> 6);
                s_m8[word] = bm;
                __hip_atomic_store(&xmb[(size_t)t * 8 + word], bm,
                                   __ATOMIC_RELAXED, __HIP_MEMORY_SCOPE_AGENT);
                __hip_atomic_store(&xfb[(size_t)t * 8 + word], 1u,
                                   __ATOMIC_RELEASE, __HIP_MEMORY_SCOPE_AGENT);
            }
        }

        // ---- thread 0: poll remote flags, fetch remote mask words ----
        if (tid == 0) {
            const uint32_t need = 0xFFu & ~(3u << (2 * j));
            uint32_t* fl = &xfb[(size_t)t * 8];
            uint32_t got = 0;
            long guard = 0;
            while ((got & need) != need && guard < 1000000000L) {
                got = 0;
#pragma unroll
                for (int s = 0; s < 8; ++s) {
                    if (need & (1u << s)) {
                        if (__hip_atomic_load(&fl[s], __ATOMIC_RELAXED,
                                              __HIP_MEMORY_SCOPE_AGENT) == 1u)
                            got |= (1u << s);
                    }
                }
                ++guard;
            }
            __builtin_amdgcn_fence(__ATOMIC_ACQUIRE, "agent");
            uint64_t* xw = &xmb[(size_t)t * 8];
#pragma unroll
            for (int s = 0; s < 8; ++s) {
                if (need & (1u << s))
                    s_m8[s] = __hip_atomic_load(&xw[s], __ATOMIC_RELAXED,
                                                __HIP_MEMORY_SCOPE_AGENT);
            }
        }
        __syncthreads();  // B3: all 8 mask words in s_m8

        // ---- build next active list (deterministic prefix popcount) ----
        if (tid < HH) {
            uint64_t m[8];
#pragma unroll
            for (int s = 0; s < 8; ++s) m[s] = s_m8[s];
            const int ww = tid >> 6, bit = tid & 63;
            if ((m[ww] >> bit) & 1ull) {
                int base = 0;
#pragma unroll
                for (int s = 0; s < 8; ++s)
                    if (s < ww) base += __popcll(m[s]);
                base += __popcll(m[ww] & ((1ull << bit) - 1ull));
                s_act[nxt][base] = tid << 11;  // h * 2048 bytes
            }
        } else if (tid == HH) {
            int tot = 0;
#pragma unroll
            for (int s = 0; s < 8; ++s) tot += __popcll(s_m8[s]);
            s_nact[nxt] = tot;
        }
        __syncthreads();  // B4: next list ready
        cur = nxt;
    }
}

// ---------------- Phase 3: sparse output GEMM from bitmasks ----------------
__global__ __launch_bounds__(256) void out_gemm(const uint64_t* __restrict__ masks,
                                                const float* __restrict__ wout,
                                                float* __restrict__ out) {
    const int bt = blockIdx.x;
    const int o = threadIdx.x;
    __shared__ uint64_t sm[8];
    if (o < 8) sm[o] = masks[(size_t)bt * 8 + o];
    __syncthreads();

    float acc = 0.0f;
#pragma unroll
    for (int w = 0; w < 8; ++w) {
        uint64_t bits = sm[w];
        while (bits) {
            const int h = (w << 6) + __ffsll((unsigned long long)bits) - 1;
            bits &= bits - 1;
            acc += wout[(size_t)h * OO + o];
        }
    }
    out[(size_t)bt * OO + o] = acc;
}

extern "C" void kernel_launch(void* const* d_in, const int* in_sizes, int n_in,
                              void* d_out, int out_size, void* d_ws, size_t ws_size,
                              hipStream_t stream) {
    const float* x    = (const float*)d_in[0];  // [B, S, I]
    const float* win  = (const float*)d_in[1];  // [I, H]
    const float* wlat = (const float*)d_in[2];  // [H, H]
    const float* wout = (const float*)d_in[3];  // [H, O]
    const float* thr  = (const float*)d_in[4];  // [H]
    float* out = (float*)d_out;                 // [B, S, O]

    // Workspace: ic f64 (134.2MB) | xm/masks (2MB) | wpad (1.05MB) | xf (1MB)
    char* p = (char*)d_ws;
    double* ic = (double*)p;        p += (size_t)BB * SS * HH * sizeof(double);
    uint64_t* xm = (uint64_t*)p;    p += (size_t)BB * SS * 8 * sizeof(uint64_t);
    float* wpad = (float*)p;        p += (size_t)(HH + 1) * HH * sizeof(float);
    uint32_t* xf = (uint32_t*)p;

    const int M = BB * SS;  // 32768
    wlat_pad<<<((HH + 1) * HH + 255) / 256, 256, 0, stream>>>(wlat, wpad);
    ic_gemm_f64<<<dim3(M / TM, HH / TN), 256, 0, stream>>>(x, win, ic);
    snn_scan4<<<BB * NSPL, 1024, 0, stream>>>(ic, wpad, thr, xm, xf);
    out_gemm<<<M, 256, 0, stream>>>(xm, wout, out);
}

// Round 8
// 2749.165 us; speedup vs baseline: 2.1725x; 2.1725x over previous
//
#include <hip/hip_runtime.h>
#include <stdint.h>

// Spiking neural network:
//   B=32 batches, S=1024 steps, I=256 inputs, H=512 hidden, O=256 outputs.
// Phase 1: ic[B*S, H] (f64) = x[B*S, I] @ Win[I, H]   (feeds spike decisions)
// Phase 2: 8-way column-split scan: 8 blocks per batch, each owns 64 neurons.
//          Per-step mask exchange via self-validating write-once pair cells
//          (v, v^MAGIC) polled with parallel lanes — ONE LLC round trip.
// Phase 3: out[B*S, O] (f32) = spikes @ Wout via bitmask-driven row sums.
//
// All decision-feeding arithmetic is f64 so spikes match an f64 numpy
// reference exactly; split/order nondeterminism only perturbs sums ~1e-15.

#define BB 32
#define SS 1024
#define II 256
#define HH 512
#define OO 256
#define NSPL 8
#define MAGICK 0x5A5A5A5A5A5A5A5AULL

// ---------------- Phase 1: f64-accumulate tiled GEMM ----------------
#define TM 64
#define TN 64
#define TK 16

__global__ __launch_bounds__(256) void ic_gemm_f64(const float* __restrict__ x,
                                                   const float* __restrict__ win,
                                                   double* __restrict__ ic) {
    __shared__ float As[TK][TM + 4];
    __shared__ float Bs[TK][TN];
    const int tid = threadIdx.x;
    const int m0 = blockIdx.x * TM;
    const int n0 = blockIdx.y * TN;
    const int tx = tid & 15;
    const int ty = tid >> 4;

    double acc[4][4];
#pragma unroll
    for (int i = 0; i < 4; ++i)
#pragma unroll
        for (int j = 0; j < 4; ++j) acc[i][j] = 0.0;

    const int lr = tid >> 2;
    const int lq = tid & 3;
    const int br = tid >> 4;
    const int bq = tid & 15;

    for (int k0 = 0; k0 < II; k0 += TK) {
        float4 av = *(const float4*)(x + (size_t)(m0 + lr) * II + k0 + lq * 4);
        float4 bv = *(const float4*)(win + (size_t)(k0 + br) * HH + n0 + bq * 4);
        As[lq * 4 + 0][lr] = av.x;
        As[lq * 4 + 1][lr] = av.y;
        As[lq * 4 + 2][lr] = av.z;
        As[lq * 4 + 3][lr] = av.w;
        *(float4*)(&Bs[br][bq * 4]) = bv;
        __syncthreads();
#pragma unroll
        for (int kk = 0; kk < TK; ++kk) {
            float4 a = *(const float4*)(&As[kk][ty * 4]);
            float4 b = *(const float4*)(&Bs[kk][tx * 4]);
            const double a0 = (double)a.x, a1 = (double)a.y, a2 = (double)a.z, a3 = (double)a.w;
            const double b0 = (double)b.x, b1 = (double)b.y, b2 = (double)b.z, b3 = (double)b.w;
            acc[0][0] += a0 * b0; acc[0][1] += a0 * b1; acc[0][2] += a0 * b2; acc[0][3] += a0 * b3;
            acc[1][0] += a1 * b0; acc[1][1] += a1 * b1; acc[1][2] += a1 * b2; acc[1][3] += a1 * b3;
            acc[2][0] += a2 * b0; acc[2][1] += a2 * b1; acc[2][2] += a2 * b2; acc[2][3] += a2 * b3;
            acc[3][0] += a3 * b0; acc[3][1] += a3 * b1; acc[3][2] += a3 * b2; acc[3][3] += a3 * b3;
        }
        __syncthreads();
    }

#pragma unroll
    for (int i = 0; i < 4; ++i) {
        double* row = ic + (size_t)(m0 + ty * 4 + i) * HH + n0 + tx * 4;
#pragma unroll
        for (int j = 0; j < 4; ++j) row[j] = acc[i][j];
    }
}

// ---------------- Phase 2: 8-way split sequential scan ----------------
// Grid: 256 blocks x 256 threads. bid = j*32 + b  (j = split, owns columns
// [64j, 64j+64)); all 8 blocks of a batch are co-resident (1 block/CU).
// Gather: chunk ch = tid>>4 (16 chunks) processes active rows ch, ch+16, ...;
// quad qd = tid&15 reads 4 adjacent columns (16B) of the block's 64-col slice
// straight from wlat (L2-resident). Exact per-chunk counts; act list padded
// with row 0 so rotation over-reads are valid and never accumulated.
// Exchange: xq[b][t][w][2] u64 pair cells (bm, bm^MAGIC), write-once,
// relaxed agent atomics; 16 lanes poll all remote pairs in parallel.
__global__ __launch_bounds__(256) void snn_scan8(const double* __restrict__ ic,
                                                 const float* __restrict__ wlat,
                                                 const float* __restrict__ thr,
                                                 uint64_t* __restrict__ xq) {
    __shared__ int s_act[2][560];
    __shared__ int s_nact[2];
    __shared__ double s_part[16][68];
    __shared__ uint64_t s_m8[8];

    const int tid = threadIdx.x;
    const int bid = blockIdx.x;
    const int b = bid & 31;
    const int j = bid >> 5;          // split index: same-XCD peers under %8 rr
    const int ch = tid >> 4;
    const int qd = tid & 15;
    const int sw = (qd >> 2) & 3;

    const double* icb = ic + (size_t)b * SS * HH + (j << 6);
    uint64_t* xqb = xq + ((size_t)b * SS << 4);
    const char* wb = (const char*)wlat + (j << 8) + (qd << 4);

    const bool owner = (tid < 64);
    double mp = 0.0, th = 0.0, icv = 0.0;
    int refrac = 0, rsw = 0;
    if (owner) {
        th = (double)thr[(j << 6) + tid];
        rsw = tid ^ ((tid >> 4) & 3);
        icv = icb[tid];               // prefetch ic for t=0
    }
    if (tid == 0) { s_nact[0] = 0; s_nact[1] = 0; }
    for (int i = tid; i < 560; i += 256) { s_act[0][i] = 0; s_act[1][i] = 0; }
    __syncthreads();

    int cur = 0;
    for (int t = 0; t < SS; ++t) {
        const int nxt = cur ^ 1;

        // ---- gather phase: lateral partial sums from wlat (L2) ----
        const int n = s_nact[cur];
        const int* act = s_act[cur];
        const int kcnt = (n > ch) ? ((n - ch + 15) >> 4) : 0;

        double ac0 = 0.0, ac1 = 0.0, ac2 = 0.0, ac3 = 0.0;
        {
            int idx = ch;
            float4 f0 = *(const float4*)(wb + act[idx]);
            float4 f1 = *(const float4*)(wb + act[idx + 16]);
            for (int k = 0; k < kcnt; ++k) {
                float4 f2 = *(const float4*)(wb + act[idx + 32]);
                ac0 += (double)f0.x;
                ac1 += (double)f0.y;
                ac2 += (double)f0.z;
                ac3 += (double)f0.w;
                f0 = f1; f1 = f2; idx += 16;
            }
        }
        {
            const int pb = qd << 2;
            s_part[ch][(pb + 0) ^ sw] = ac0;
            s_part[ch][(pb + 1) ^ sw] = ac1;
            s_part[ch][(pb + 2) ^ sw] = ac2;
            s_part[ch][(pb + 3) ^ sw] = ac3;
        }
        __syncthreads();  // B1: partials ready

        if (owner) {
            // ---- reduce + membrane update + ballot + publish ----
            double l0 = 0.0, l1 = 0.0, l2 = 0.0, l3 = 0.0;
#pragma unroll
            for (int c = 0; c < 16; c += 4) {
                l0 += s_part[c + 0][rsw];
                l1 += s_part[c + 1][rsw];
                l2 += s_part[c + 2][rsw];
                l3 += s_part[c + 3][rsw];
            }
            const double lat = (l0 + l1) + (l2 + l3);
            mp = 0.95 * mp + icv - lat;
            if (refrac > 0) mp = 0.0;
            refrac = (refrac > 0) ? (refrac - 1) : 0;
            const bool spike = (mp >= th);
            if (spike) { mp = 0.0; refrac = 2; }

            const uint64_t bm = __ballot(spike);
            if (tid == 0) {
                uint64_t* cell = xqb + ((size_t)t << 4) + (j << 1);
                __hip_atomic_store(cell, bm, __ATOMIC_RELAXED,
                                   __HIP_MEMORY_SCOPE_AGENT);
                __hip_atomic_store(cell + 1, bm ^ MAGICK, __ATOMIC_RELAXED,
                                   __HIP_MEMORY_SCOPE_AGENT);
                s_m8[j] = bm;
            }

            // ---- parallel pair-poll of the 7 remote words (1 LLC trip) ----
            if (tid < 16) {
                const int w = tid & 7;
                if (w != j) {
                    uint64_t* rc = xqb + ((size_t)t << 4) + (w << 1) + (tid >> 3);
                    long guard = 0;
                    uint64_t v;
                    for (;;) {
                        v = __hip_atomic_load(rc, __ATOMIC_RELAXED,
                                              __HIP_MEMORY_SCOPE_AGENT);
                        const uint64_t pv = __shfl(v, tid ^ 8, 64);
                        if ((v ^ pv) == MAGICK) break;      // pair complete
                        if (++guard > (1L << 31)) break;    // loud fail, no hang
                    }
                    if (tid < 8) s_m8[w] = v;
                }
            }
            // prefetch next step's ic (hidden under build + next gather)
            icv = icb[(size_t)(t < SS - 1 ? t + 1 : t) * HH + tid];
        } else {
            // waves 1-3: re-pad next act buffer (last read 2+ barriers ago)
            for (int i = tid - 64; i < 560; i += 192) s_act[nxt][i] = 0;
        }
        __syncthreads();  // B2: s_m8 + padding ready

        // ---- build next active list (all 256 threads, 2 neurons each) ----
        {
            int rr = tid;
#pragma unroll
            for (int pass = 0; pass < 2; ++pass, rr += 256) {
                const int w = rr >> 6, bit = rr & 63;
                int base = 0, tot = 0;
                uint64_t myw = 0;
#pragma unroll
                for (int u = 0; u < 8; ++u) {
                    const uint64_t mw = s_m8[u];
                    const int pc = __popcll(mw);
                    if (u < w) base += pc;
                    if (u == w) myw = mw;
                    tot += pc;
                }
                if ((myw >> bit) & 1ull)
                    s_act[nxt][base + __popcll(myw & ((1ull << bit) - 1ull))] =
                        rr << 11;  // row byte offset r*2048
                if (tid == 0 && pass == 0) s_nact[nxt] = tot;
            }
        }
        __syncthreads();  // B3: next list ready
        cur = nxt;
    }
}

// ---------------- Phase 3: sparse output GEMM from pair cells ----------------
__global__ __launch_bounds__(256) void out_gemm(const uint64_t* __restrict__ xq,
                                                const float* __restrict__ wout,
                                                float* __restrict__ out) {
    const int bt = blockIdx.x;
    const int o = threadIdx.x;
    __shared__ uint64_t sm[8];
    if (o < 8) sm[o] = xq[((size_t)bt << 4) + (o << 1)];
    __syncthreads();

    float acc = 0.0f;
#pragma unroll
    for (int w = 0; w < 8; ++w) {
        uint64_t bits = sm[w];
        while (bits) {
            const int h = (w << 6) + __ffsll((unsigned long long)bits) - 1;
            bits &= bits - 1;
            acc += wout[(size_t)h * OO + o];
        }
    }
    out[(size_t)bt * OO + o] = acc;
}

extern "C" void kernel_launch(void* const* d_in, const int* in_sizes, int n_in,
                              void* d_out, int out_size, void* d_ws, size_t ws_size,
                              hipStream_t stream) {
    const float* x    = (const float*)d_in[0];  // [B, S, I]
    const float* win  = (const float*)d_in[1];  // [I, H]
    const float* wlat = (const float*)d_in[2];  // [H, H]
    const float* wout = (const float*)d_in[3];  // [H, O]
    const float* thr  = (const float*)d_in[4];  // [H]
    float* out = (float*)d_out;                 // [B, S, O]

    // Workspace: ic f64 (128 MiB) | xq pair cells (4 MiB) = 132 MiB
    char* p = (char*)d_ws;
    double* ic = (double*)p;      p += (size_t)BB * SS * HH * sizeof(double);
    uint64_t* xq = (uint64_t*)p;

    const int M = BB * SS;  // 32768
    ic_gemm_f64<<<dim3(M / TM, HH / TN), 256, 0, stream>>>(x, win, ic);
    snn_scan8<<<BB * NSPL, 256, 0, stream>>>(ic, wlat, thr, xq);
    out_gemm<<<M, 256, 0, stream>>>(xq, wout, out);
}